// Round 11
// baseline (427.378 us; speedup 1.0000x reference)
//
#include <hip/hip_runtime.h>

// ---------------------------------------------------------------------------
// Attention block: out = SDPA(RoPE(x@wq^T), RoPE(x@wk^T), x@wv^T) @ wo^T
// B=2 S=2048 D=2048 H=16 HD=128, causal, start_pos=0.
// R16 = R15 with the launcher typo fixed: gemm_out must be <<<256, 512>>>
//      (R15 accidentally launched <<<512, 256>>> -> m0 up to 7936 > M=4096
//      -> OOB stores on d_out -> core dump). No other changes.
//      GEMMs: R11-exact 16x16x32 depth-2 BK=64 counted-vmcnt pipeline.
//      flash_attn: V LDS staging removed (V^T L2-resident; PV reads global
//      directly); K stays LDS double-buffered; LDS 48 KB.
// ---------------------------------------------------------------------------

typedef __bf16 bf16_t;
typedef __bf16 bf16x4 __attribute__((ext_vector_type(4)));
typedef __bf16 bf16x8 __attribute__((ext_vector_type(8)));
typedef float  f32x4  __attribute__((ext_vector_type(4)));

#define DEV __device__ __forceinline__

DEV void async_copy16(const bf16_t* g, bf16_t* lds_uniform_base) {
    __builtin_amdgcn_global_load_lds(
        (const __attribute__((address_space(1))) void*)g,
        (__attribute__((address_space(3))) void*)lds_uniform_base,
        16, 0, 0);
}

#define BAR    __builtin_amdgcn_s_barrier()
#define VMC(n) asm volatile("s_waitcnt vmcnt(" #n ")" ::: "memory")

// ---------------------------------------------------------------------------
__global__ void cast_all(const float* __restrict__ x,  const float* __restrict__ wq,
                         const float* __restrict__ wk, const float* __restrict__ wv,
                         const float* __restrict__ wo,
                         bf16_t* __restrict__ xb, bf16_t* __restrict__ W3,
                         bf16_t* __restrict__ wob)
{
    const int i = blockIdx.x * blockDim.x + threadIdx.x;
    const float4* src;
    bf16x4* dst;
    if (i < 2097152) {
        src = (const float4*)x + i;
        dst = (bf16x4*)xb + i;
    } else {
        const int j   = i - 2097152;
        const int r   = j >> 20;
        const int off = j & 1048575;
        const float* s4 = (r == 0) ? wq : (r == 1) ? wk : (r == 2) ? wv : wo;
        src = (const float4*)s4 + off;
        dst = (r < 3) ? ((bf16x4*)W3 + (long)r * 1048576 + off)
                      : ((bf16x4*)wob + off);
    }
    const float4 v = *src;
    bf16x4 o = { (bf16_t)v.x, (bf16_t)v.y, (bf16_t)v.z, (bf16_t)v.w };
    *dst = o;
}

// ---------------------------------------------------------------------------
// Fused QKV projection: C = x(4096x2048) * W3(6144x2048)^T. 256x128 tile,
// BK=64, 3-buffer depth-2 pipeline, counted vmcnt, 16x16x32 MFMA
// (R11-exact; measured conflict-free).
// n in [0,2048): RoPE -> Q ; [2048,4096): RoPE -> K ; [4096,6144): V^T.
// V^T layout: VT[((b*16+h)*128 + d)*2048 + s]
// ---------------------------------------------------------------------------
__global__ __launch_bounds__(512)
void gemm_qkv(const bf16_t* __restrict__ A, const bf16_t* __restrict__ Bm,
              bf16_t* __restrict__ Qo, bf16_t* __restrict__ Ko,
              bf16_t* __restrict__ VTo,
              const float* __restrict__ cosT, const float* __restrict__ sinT)
{
    constexpr int K = 2048;                 // 32 k-tiles of 64
    __shared__ bf16_t As[3][16384];         // [buf][256 rows x 64 k]
    __shared__ bf16_t Bs[3][8192];          // [buf][128 rows x 64 k]

    const int tid  = threadIdx.x;
    const int w    = tid >> 6;              // 0..7
    const int lane = tid & 63;
    const int l16  = lane & 15;
    const int quad = lane >> 4;
    const int l7   = l16 & 7;
    const int wm   = w >> 1;                // 0..3 (M quarter)
    const int wn   = w & 1;                 // 0..1 (N half)

    const int id   = blockIdx.x;            // 768 = 16 M x 48 N
    const int xcd  = id & 7;
    const int slot = id >> 3;               // 0..95
    const int nl   = slot % 6;
    const int ml   = slot / 6;              // 0..15
    const long n0  = (long)(xcd * 6 + nl) * 128;
    const long m0  = (long)ml * 256;

    f32x4 acc[4][4] = {};

    // staging: A 2048 chunks (4/thread), B 1024 chunks (2/thread)
    const bf16_t* Ag[4];
    const bf16_t* Bg[2];
    #pragma unroll
    for (int i = 0; i < 4; ++i) {
        const int c   = i * 512 + tid;
        const int row = c >> 3;
        const int col = ((c & 7) ^ (row & 7)) * 8;
        Ag[i] = A + (m0 + row) * K + col;
    }
    #pragma unroll
    for (int i = 0; i < 2; ++i) {
        const int c   = i * 512 + tid;
        const int row = c >> 3;
        const int col = ((c & 7) ^ (row & 7)) * 8;
        Bg[i] = Bm + (n0 + row) * K + col;
    }

#define STAGE(t, bu) {                                                        \
    _Pragma("unroll") for (int i = 0; i < 4; ++i)                             \
        async_copy16(Ag[i] + (t) * 64, &As[bu][i * 4096 + w * 512]);          \
    _Pragma("unroll") for (int i = 0; i < 2; ++i)                             \
        async_copy16(Bg[i] + (t) * 64, &Bs[bu][i * 4096 + w * 512]); }

#define COMP(bu) {                                                            \
    _Pragma("unroll") for (int kc = 0; kc < 2; ++kc) {                        \
        bf16x8 af[4], bfr[4];                                                 \
        const int cs = ((kc * 4 + quad) ^ l7) * 8;                            \
        _Pragma("unroll") for (int t = 0; t < 4; ++t) {                       \
            af[t]  = *(const bf16x8*)&As[bu][(wm * 64 + t * 16 + l16) * 64 + cs]; \
            bfr[t] = *(const bf16x8*)&Bs[bu][(wn * 64 + t * 16 + l16) * 64 + cs]; \
        }                                                                     \
        _Pragma("unroll") for (int mt = 0; mt < 4; ++mt)                      \
            _Pragma("unroll") for (int nt = 0; nt < 4; ++nt)                  \
                acc[mt][nt] = __builtin_amdgcn_mfma_f32_16x16x32_bf16(        \
                    af[mt], bfr[nt], acc[mt][nt], 0, 0, 0); } }

    // prologue: tiles 0,1 in flight (12 loads/thread)
    STAGE(0, 0); STAGE(1, 1);

    // main loop: j = 0..29, stage j+2, unrolled x3 for static buffer idx
    #pragma unroll 1
    for (int jb = 0; jb < 30; jb += 3) {
        VMC(6); BAR; STAGE(jb + 2, 2); COMP(0);
        VMC(6); BAR; STAGE(jb + 3, 0); COMP(1);
        VMC(6); BAR; STAGE(jb + 4, 1); COMP(2);
    }
    VMC(6); BAR; COMP(0);   // j=30 (tile 31 outstanding)
    VMC(0); BAR; COMP(1);   // j=31

#undef STAGE
#undef COMP

    const int region = (int)(n0 >> 11);   // block-uniform: 0=Q, 1=K, 2=V
    #pragma unroll
    for (int mt = 0; mt < 4; ++mt) {
        #pragma unroll
        for (int nt = 0; nt < 4; ++nt) {
            if (region < 2) {
                bf16_t* dst = (region == 0) ? Qo : Ko;
                #pragma unroll
                for (int r = 0; r < 4; ++r) {
                    const long m = m0 + wm * 64 + mt * 16 + quad * 4 + r;
                    const long n = n0 + wn * 64 + nt * 16 + l16;
                    float v = acc[mt][nt][r];
                    const float partner = __shfl_xor(v, 1);
                    const int d    = (int)n & 127;
                    const int fidx = ((int)m & 2047) * 64 + (d >> 1);
                    const float c = cosT[fidx], s = sinT[fidx];
                    v = ((int)n & 1) ? fmaf(partner, s, v * c)
                                     : (v * c - partner * s);
                    dst[m * 2048 + (n & 2047)] = (bf16_t)v;
                }
            } else {
                const long m  = m0 + wm * 64 + mt * 16 + quad * 4;   // r=0 base
                const int  np = (int)(n0 + wn * 64 + nt * 16 + l16) - 4096;
                bf16x4 pk;
                #pragma unroll
                for (int r = 0; r < 4; ++r) pk[r] = (bf16_t)acc[mt][nt][r];
                const int b  = (int)(m >> 11);
                const int s0 = (int)m & 2047;
                const long idx = ((long)(b * 16 + (np >> 7)) * 128 + (np & 127)) * 2048 + s0;
                *(bf16x4*)&VTo[idx] = pk;
            }
        }
    }
}

// ---------------------------------------------------------------------------
// Output projection: C = Ob(4096x2048) * wo(2048x2048)^T -> fp32.
// Same 256x128 depth-2 BK=64 pipeline as gemm_qkv (R11-exact).
// Launch: <<<256, 512>>> (256 blocks = 16 M x 16 N).
// ---------------------------------------------------------------------------
__global__ __launch_bounds__(512)
void gemm_out(const bf16_t* __restrict__ A, const bf16_t* __restrict__ Bm,
              float* __restrict__ Cp)
{
    constexpr int K = 2048, N = 2048;
    __shared__ bf16_t As[3][16384];
    __shared__ bf16_t Bs[3][8192];

    const int tid  = threadIdx.x;
    const int w    = tid >> 6;
    const int lane = tid & 63;
    const int l16  = lane & 15;
    const int quad = lane >> 4;
    const int l7   = l16 & 7;
    const int wm   = w >> 1, wn = w & 1;

    const int id   = blockIdx.x;            // 256 = 16 M x 16 N
    const int xcd  = id & 7;
    const int slot = id >> 3;               // 0..31
    const long n0  = (long)(xcd * 2 + (slot & 1)) * 128;
    const long m0  = (long)(slot >> 1) * 256;

    f32x4 acc[4][4] = {};

    const bf16_t* Ag[4];
    const bf16_t* Bg[2];
    #pragma unroll
    for (int i = 0; i < 4; ++i) {
        const int c   = i * 512 + tid;
        const int row = c >> 3;
        const int col = ((c & 7) ^ (row & 7)) * 8;
        Ag[i] = A + (m0 + row) * K + col;
    }
    #pragma unroll
    for (int i = 0; i < 2; ++i) {
        const int c   = i * 512 + tid;
        const int row = c >> 3;
        const int col = ((c & 7) ^ (row & 7)) * 8;
        Bg[i] = Bm + (n0 + row) * K + col;
    }

#define STAGE(t, bu) {                                                        \
    _Pragma("unroll") for (int i = 0; i < 4; ++i)                             \
        async_copy16(Ag[i] + (t) * 64, &As[bu][i * 4096 + w * 512]);          \
    _Pragma("unroll") for (int i = 0; i < 2; ++i)                             \
        async_copy16(Bg[i] + (t) * 64, &Bs[bu][i * 4096 + w * 512]); }

#define COMP(bu) {                                                            \
    _Pragma("unroll") for (int kc = 0; kc < 2; ++kc) {                        \
        bf16x8 af[4], bfr[4];                                                 \
        const int cs = ((kc * 4 + quad) ^ l7) * 8;                            \
        _Pragma("unroll") for (int t = 0; t < 4; ++t) {                       \
            af[t]  = *(const bf16x8*)&As[bu][(wm * 64 + t * 16 + l16) * 64 + cs]; \
            bfr[t] = *(const bf16x8*)&Bs[bu][(wn * 64 + t * 16 + l16) * 64 + cs]; \
        }                                                                     \
        _Pragma("unroll") for (int mt = 0; mt < 4; ++mt)                      \
            _Pragma("unroll") for (int nt = 0; nt < 4; ++nt)                  \
                acc[mt][nt] = __builtin_amdgcn_mfma_f32_16x16x32_bf16(        \
                    af[mt], bfr[nt], acc[mt][nt], 0, 0, 0); } }

    STAGE(0, 0); STAGE(1, 1);

    #pragma unroll 1
    for (int jb = 0; jb < 30; jb += 3) {
        VMC(6); BAR; STAGE(jb + 2, 2); COMP(0);
        VMC(6); BAR; STAGE(jb + 3, 0); COMP(1);
        VMC(6); BAR; STAGE(jb + 4, 1); COMP(2);
    }
    VMC(6); BAR; COMP(0);
    VMC(0); BAR; COMP(1);

#undef STAGE
#undef COMP

    #pragma unroll
    for (int mt = 0; mt < 4; ++mt)
        #pragma unroll
        for (int nt = 0; nt < 4; ++nt)
            #pragma unroll
            for (int r = 0; r < 4; ++r) {
                const long m = m0 + wm * 64 + mt * 16 + quad * 4 + r;
                const long n = n0 + wn * 64 + nt * 16 + l16;
                Cp[m * N + n] = acc[mt][nt][r];
            }
}

// ---------------------------------------------------------------------------
// Flash attention R15/R16. Grid 512, 4 waves; 128-row Q tile. V LDS staging
// removed: PV reads V^T directly from global (L2-resident, 512 KB/bh shared
// by 16 blocks; lanes' quad spread -> 64B-line sectored reads). K stays
// LDS double-buffered (reused by all 4 waves, conflict-free swizzle).
// LDS = 32K(Kb) + 16K(Ps) = 48 KB.
// ---------------------------------------------------------------------------
__global__ __launch_bounds__(256, 2)
void flash_attn(const bf16_t* __restrict__ Q, const bf16_t* __restrict__ Kg,
                const bf16_t* __restrict__ VT, bf16_t* __restrict__ O)
{
    constexpr int S = 2048, D = 2048;
    __shared__ bf16_t Kb[2][64 * 128];   // [k_row][d], chunk-swizzled
    __shared__ bf16_t Ps[128 * 64];      // [q_row][k], XOR chunk-swizzled

    const int tid  = threadIdx.x;
    const int w    = tid >> 6, lane = tid & 63, l16 = lane & 15, quad = lane >> 4;
    const int l7   = l16 & 7;
    const int rsw  = l16 & 12;           // Ps chunk swizzle (8B chunks)

    const int id   = blockIdx.x;
    const int half = id >> 8;            // 0: qt 0..7, 1: qt 15..8
    const int rest = id & 255;
    const int xcd  = rest & 7;
    const int s    = rest >> 3;          // 0..31
    const int hh   = s & 3;
    const int qh   = s >> 2;             // 0..7
    const int qt   = half ? (15 - qh) : qh;
    const int bh   = xcd * 4 + hh;
    const int b    = bh >> 4, h = bh & 15;
    const int q0   = qt * 128;

    // Q fragments (B-operand): n = q (l16), k = d
    bf16x8 qf[2][4];
    {
        const bf16_t* qp = Q + (long)(b * S + q0 + w * 32 + l16) * D + h * 128 + quad * 8;
        #pragma unroll
        for (int qi = 0; qi < 2; ++qi)
            #pragma unroll
            for (int kk = 0; kk < 4; ++kk)
                qf[qi][kk] = *(const bf16x8*)(qp + qi * 16 * D + kk * 32);
    }

    // K staging offsets (XOR chunk swizzle): 1024 chunks [64 rows][16 slots]
    int koff[4];
    #pragma unroll
    for (int i = 0; i < 4; ++i) {
        const int c  = i * 256 + tid;
        const int kr = c >> 4, cs = c & 15;
        const int cc = (cs & 8) | ((cs & 7) ^ (kr & 7));
        koff[i] = kr * D + cc * 8;
    }
    const bf16_t* Kst = Kg + (long)b * S * D + h * 128;
    // V^T read base: row = bh*128 + nv*16 + l16 (d-dim), col = k
    const bf16_t* Vg = VT + ((long)bh * 128 + l16) * S;

    f32x4 oacc[2][8] = {};
    float li[2] = { 0.f, 0.f };
    const float SC = 0.08838834764831845f * 1.44269504088896340f;

    const int nkt = 2 * qt + 2;

    // prologue: stage K[0] into buffer 0
    #pragma unroll
    for (int i = 0; i < 4; ++i)
        async_copy16(Kst + koff[i], &Kb[0][i * 2048 + w * 512]);

    for (int kt = 0; kt < nkt; ++kt) {
        __syncthreads();   // drains prefetch issued 1 iter ago; guards bufs
        // ---- prefetch next K tile (skipped on last iter) ----
        if (kt + 1 < nkt) {
            #pragma unroll
            for (int i = 0; i < 4; ++i)
                async_copy16(Kst + (long)(kt + 1) * 64 * D + koff[i],
                             &Kb[(kt + 1) & 1][i * 2048 + w * 512]);
        }

        const bool active = (kt * 64 <= q0 + w * 32 + 31);
        if (active) {
            // ---- S^T = K·Q^T ----
            f32x4 sc[4][2] = {};
            const bf16_t* Kcur = Kb[kt & 1];
            #pragma unroll
            for (int kk = 0; kk < 4; ++kk)
                #pragma unroll
                for (int mt = 0; mt < 4; ++mt) {
                    const int cc = kk * 4 + quad;
                    const bf16x8 kf = *(const bf16x8*)
                        &Kcur[(mt * 16 + l16) * 128 + ((cc & 8) | ((cc & 7) ^ l7)) * 8];
                    sc[mt][0] = __builtin_amdgcn_mfma_f32_16x16x32_bf16(
                        kf, qf[0][kk], sc[mt][0], 0, 0, 0);
                    sc[mt][1] = __builtin_amdgcn_mfma_f32_16x16x32_bf16(
                        kf, qf[1][kk], sc[mt][1], 0, 0, 0);
                }

            // ---- fixed-M softmax + packed P writes (swizzled chunks) ----
            #pragma unroll
            for (int qi = 0; qi < 2; ++qi) {
                const int qg = q0 + w * 32 + qi * 16 + l16;
                const int prow = w * 32 + qi * 16 + l16;
                float rs = 0.f;
                #pragma unroll
                for (int mt = 0; mt < 4; ++mt) {
                    bf16x4 pk;
                    #pragma unroll
                    for (int r = 0; r < 4; ++r) {
                        const int kg = kt * 64 + mt * 16 + quad * 4 + r;
                        const float p = (kg > qg) ? 0.f
                                      : exp2f(sc[mt][qi][r] * SC - 24.0f);
                        rs += p;
                        pk[r] = (bf16_t)p;
                    }
                    *(bf16x4*)&Ps[prow * 64 + ((mt * 4 + quad) ^ rsw) * 4] = pk;
                }
                li[qi] += rs;
            }

            // ---- O += P·V^T (V direct from global: L2-resident) ----
            const bf16_t* Vk = Vg + kt * 64 + quad * 8;
            #pragma unroll
            for (int ks = 0; ks < 2; ++ks) {
                const bf16x8 pf0 = *(const bf16x8*)
                    &Ps[(w * 32 + l16) * 64 + ((ks * 8 + quad * 2) ^ rsw) * 4];
                const bf16x8 pf1 = *(const bf16x8*)
                    &Ps[(w * 32 + 16 + l16) * 64 + ((ks * 8 + quad * 2) ^ rsw) * 4];
                #pragma unroll
                for (int nv = 0; nv < 8; ++nv) {
                    const bf16x8 vf = *(const bf16x8*)(Vk + (long)nv * 16 * S + ks * 32);
                    oacc[0][nv] = __builtin_amdgcn_mfma_f32_16x16x32_bf16(
                        pf0, vf, oacc[0][nv], 0, 0, 0);
                    oacc[1][nv] = __builtin_amdgcn_mfma_f32_16x16x32_bf16(
                        pf1, vf, oacc[1][nv], 0, 0, 0);
                }
            }
        }
    }

    // ---- epilogue: reduce li across quads, normalize, store ----
    #pragma unroll
    for (int qi = 0; qi < 2; ++qi) {
        li[qi] += __shfl_xor(li[qi], 16);
        li[qi] += __shfl_xor(li[qi], 32);
        const float inv = 1.0f / li[qi];
        #pragma unroll
        for (int r = 0; r < 4; ++r) {
            const float invr = __shfl(inv, quad * 4 + r);
            const long  row  = (long)(b * S + q0 + w * 32 + qi * 16 + quad * 4 + r);
            #pragma unroll
            for (int nv = 0; nv < 8; ++nv)
                O[row * D + h * 128 + nv * 16 + l16] = (bf16_t)(oacc[qi][nv][r] * invr);
        }
    }
}

// ---------------------------------------------------------------------------
extern "C" void kernel_launch(void* const* d_in, const int* in_sizes, int n_in,
                              void* d_out, int out_size, void* d_ws, size_t ws_size,
                              hipStream_t stream) {
    const float* x  = (const float*)d_in[0];
    const float* wq = (const float*)d_in[1];
    const float* wk = (const float*)d_in[2];
    const float* wv = (const float*)d_in[3];
    const float* wo = (const float*)d_in[4];
    const float* fc = (const float*)d_in[5];
    const float* fs = (const float*)d_in[6];

    char* ws = (char*)d_ws;
    bf16_t* xb  = (bf16_t*)(ws + 0);
    bf16_t* W3  = (bf16_t*)(ws + (16l << 20));
    bf16_t* wob = (bf16_t*)(ws + (40l << 20));
    bf16_t* Qb  = (bf16_t*)(ws + (48l << 20));
    bf16_t* Kb  = (bf16_t*)(ws + (64l << 20));
    bf16_t* VTb = (bf16_t*)(ws + (80l << 20));
    bf16_t* Ob  = xb;   // x dead after QKV projection

    cast_all<<<24576, 256, 0, stream>>>(x, wq, wk, wv, wo, xb, W3, wob);

    gemm_qkv<<<768, 512, 0, stream>>>(xb, W3, Qb, Kb, VTb, fc, fs);

    flash_attn<<<512, 256, 0, stream>>>(Qb, Kb, VTb, Ob);

    gemm_out<<<256, 512, 0, stream>>>(Ob, wob, (float*)d_out);
}

// Round 12
// 360.187 us; speedup vs baseline: 1.1865x; 1.1865x over previous
//
#include <hip/hip_runtime.h>

// ---------------------------------------------------------------------------
// Attention block: out = SDPA(RoPE(x@wq^T), RoPE(x@wk^T), x@wv^T) @ wo^T
// B=2 S=2048 D=2048 H=16 HD=128, causal, start_pos=0.
// R17: revert R16's V-direct (4 waves each re-read the V tile from L2 ->
//      4x traffic on the PV critical path; MfmaUtil fell to 10%). flash
//      back to R14 structure (Vb LDS-staged, last-iter refetch dropped,
//      no setprio) with a FIXED Ps swizzle: old mask (l16&12) ignored row
//      bits 0-1 -> 4-way bank conflict on bf16x4 writes (5.9M measured).
//      New mask ((l16&3)<<2)^((l16&12)>>1): even (16B read pairs intact),
//      every value hit exactly 2x across l16 -> 2-way = free.
//      GEMMs: R11-exact 16x16 depth-2 BK=64 pipeline (112 us, 0 conflicts).
// ---------------------------------------------------------------------------

typedef __bf16 bf16_t;
typedef __bf16 bf16x4 __attribute__((ext_vector_type(4)));
typedef __bf16 bf16x8 __attribute__((ext_vector_type(8)));
typedef float  f32x4  __attribute__((ext_vector_type(4)));

#define DEV __device__ __forceinline__

DEV void async_copy16(const bf16_t* g, bf16_t* lds_uniform_base) {
    __builtin_amdgcn_global_load_lds(
        (const __attribute__((address_space(1))) void*)g,
        (__attribute__((address_space(3))) void*)lds_uniform_base,
        16, 0, 0);
}

#define BAR    __builtin_amdgcn_s_barrier()
#define VMC(n) asm volatile("s_waitcnt vmcnt(" #n ")" ::: "memory")

// ---------------------------------------------------------------------------
__global__ void cast_all(const float* __restrict__ x,  const float* __restrict__ wq,
                         const float* __restrict__ wk, const float* __restrict__ wv,
                         const float* __restrict__ wo,
                         bf16_t* __restrict__ xb, bf16_t* __restrict__ W3,
                         bf16_t* __restrict__ wob)
{
    const int i = blockIdx.x * blockDim.x + threadIdx.x;
    const float4* src;
    bf16x4* dst;
    if (i < 2097152) {
        src = (const float4*)x + i;
        dst = (bf16x4*)xb + i;
    } else {
        const int j   = i - 2097152;
        const int r   = j >> 20;
        const int off = j & 1048575;
        const float* s4 = (r == 0) ? wq : (r == 1) ? wk : (r == 2) ? wv : wo;
        src = (const float4*)s4 + off;
        dst = (r < 3) ? ((bf16x4*)W3 + (long)r * 1048576 + off)
                      : ((bf16x4*)wob + off);
    }
    const float4 v = *src;
    bf16x4 o = { (bf16_t)v.x, (bf16_t)v.y, (bf16_t)v.z, (bf16_t)v.w };
    *dst = o;
}

// ---------------------------------------------------------------------------
// Fused QKV projection: C = x(4096x2048) * W3(6144x2048)^T. 256x128 tile,
// BK=64, 3-buffer depth-2 pipeline, counted vmcnt, 16x16x32 MFMA
// (R11-exact; measured conflict-free).
// n in [0,2048): RoPE -> Q ; [2048,4096): RoPE -> K ; [4096,6144): V^T.
// V^T layout: VT[((b*16+h)*128 + d)*2048 + s]
// ---------------------------------------------------------------------------
__global__ __launch_bounds__(512)
void gemm_qkv(const bf16_t* __restrict__ A, const bf16_t* __restrict__ Bm,
              bf16_t* __restrict__ Qo, bf16_t* __restrict__ Ko,
              bf16_t* __restrict__ VTo,
              const float* __restrict__ cosT, const float* __restrict__ sinT)
{
    constexpr int K = 2048;                 // 32 k-tiles of 64
    __shared__ bf16_t As[3][16384];         // [buf][256 rows x 64 k]
    __shared__ bf16_t Bs[3][8192];          // [buf][128 rows x 64 k]

    const int tid  = threadIdx.x;
    const int w    = tid >> 6;              // 0..7
    const int lane = tid & 63;
    const int l16  = lane & 15;
    const int quad = lane >> 4;
    const int l7   = l16 & 7;
    const int wm   = w >> 1;                // 0..3 (M quarter)
    const int wn   = w & 1;                 // 0..1 (N half)

    const int id   = blockIdx.x;            // 768 = 16 M x 48 N
    const int xcd  = id & 7;
    const int slot = id >> 3;               // 0..95
    const int nl   = slot % 6;
    const int ml   = slot / 6;              // 0..15
    const long n0  = (long)(xcd * 6 + nl) * 128;
    const long m0  = (long)ml * 256;

    f32x4 acc[4][4] = {};

    // staging: A 2048 chunks (4/thread), B 1024 chunks (2/thread)
    const bf16_t* Ag[4];
    const bf16_t* Bg[2];
    #pragma unroll
    for (int i = 0; i < 4; ++i) {
        const int c   = i * 512 + tid;
        const int row = c >> 3;
        const int col = ((c & 7) ^ (row & 7)) * 8;
        Ag[i] = A + (m0 + row) * K + col;
    }
    #pragma unroll
    for (int i = 0; i < 2; ++i) {
        const int c   = i * 512 + tid;
        const int row = c >> 3;
        const int col = ((c & 7) ^ (row & 7)) * 8;
        Bg[i] = Bm + (n0 + row) * K + col;
    }

#define STAGE(t, bu) {                                                        \
    _Pragma("unroll") for (int i = 0; i < 4; ++i)                             \
        async_copy16(Ag[i] + (t) * 64, &As[bu][i * 4096 + w * 512]);          \
    _Pragma("unroll") for (int i = 0; i < 2; ++i)                             \
        async_copy16(Bg[i] + (t) * 64, &Bs[bu][i * 4096 + w * 512]); }

#define COMP(bu) {                                                            \
    _Pragma("unroll") for (int kc = 0; kc < 2; ++kc) {                        \
        bf16x8 af[4], bfr[4];                                                 \
        const int cs = ((kc * 4 + quad) ^ l7) * 8;                            \
        _Pragma("unroll") for (int t = 0; t < 4; ++t) {                       \
            af[t]  = *(const bf16x8*)&As[bu][(wm * 64 + t * 16 + l16) * 64 + cs]; \
            bfr[t] = *(const bf16x8*)&Bs[bu][(wn * 64 + t * 16 + l16) * 64 + cs]; \
        }                                                                     \
        _Pragma("unroll") for (int mt = 0; mt < 4; ++mt)                      \
            _Pragma("unroll") for (int nt = 0; nt < 4; ++nt)                  \
                acc[mt][nt] = __builtin_amdgcn_mfma_f32_16x16x32_bf16(        \
                    af[mt], bfr[nt], acc[mt][nt], 0, 0, 0); } }

    // prologue: tiles 0,1 in flight (12 loads/thread)
    STAGE(0, 0); STAGE(1, 1);

    // main loop: j = 0..29, stage j+2, unrolled x3 for static buffer idx
    #pragma unroll 1
    for (int jb = 0; jb < 30; jb += 3) {
        VMC(6); BAR; STAGE(jb + 2, 2); COMP(0);
        VMC(6); BAR; STAGE(jb + 3, 0); COMP(1);
        VMC(6); BAR; STAGE(jb + 4, 1); COMP(2);
    }
    VMC(6); BAR; COMP(0);   // j=30 (tile 31 outstanding)
    VMC(0); BAR; COMP(1);   // j=31

#undef STAGE
#undef COMP

    const int region = (int)(n0 >> 11);   // block-uniform: 0=Q, 1=K, 2=V
    #pragma unroll
    for (int mt = 0; mt < 4; ++mt) {
        #pragma unroll
        for (int nt = 0; nt < 4; ++nt) {
            if (region < 2) {
                bf16_t* dst = (region == 0) ? Qo : Ko;
                #pragma unroll
                for (int r = 0; r < 4; ++r) {
                    const long m = m0 + wm * 64 + mt * 16 + quad * 4 + r;
                    const long n = n0 + wn * 64 + nt * 16 + l16;
                    float v = acc[mt][nt][r];
                    const float partner = __shfl_xor(v, 1);
                    const int d    = (int)n & 127;
                    const int fidx = ((int)m & 2047) * 64 + (d >> 1);
                    const float c = cosT[fidx], s = sinT[fidx];
                    v = ((int)n & 1) ? fmaf(partner, s, v * c)
                                     : (v * c - partner * s);
                    dst[m * 2048 + (n & 2047)] = (bf16_t)v;
                }
            } else {
                const long m  = m0 + wm * 64 + mt * 16 + quad * 4;   // r=0 base
                const int  np = (int)(n0 + wn * 64 + nt * 16 + l16) - 4096;
                bf16x4 pk;
                #pragma unroll
                for (int r = 0; r < 4; ++r) pk[r] = (bf16_t)acc[mt][nt][r];
                const int b  = (int)(m >> 11);
                const int s0 = (int)m & 2047;
                const long idx = ((long)(b * 16 + (np >> 7)) * 128 + (np & 127)) * 2048 + s0;
                *(bf16x4*)&VTo[idx] = pk;
            }
        }
    }
}

// ---------------------------------------------------------------------------
// Output projection: C = Ob(4096x2048) * wo(2048x2048)^T -> fp32.
// Same 256x128 depth-2 BK=64 pipeline as gemm_qkv (R11-exact).
// Launch: <<<256, 512>>> (256 blocks = 16 M x 16 N).
// ---------------------------------------------------------------------------
__global__ __launch_bounds__(512)
void gemm_out(const bf16_t* __restrict__ A, const bf16_t* __restrict__ Bm,
              float* __restrict__ Cp)
{
    constexpr int K = 2048, N = 2048;
    __shared__ bf16_t As[3][16384];
    __shared__ bf16_t Bs[3][8192];

    const int tid  = threadIdx.x;
    const int w    = tid >> 6;
    const int lane = tid & 63;
    const int l16  = lane & 15;
    const int quad = lane >> 4;
    const int l7   = l16 & 7;
    const int wm   = w >> 1, wn = w & 1;

    const int id   = blockIdx.x;            // 256 = 16 M x 16 N
    const int xcd  = id & 7;
    const int slot = id >> 3;               // 0..31
    const long n0  = (long)(xcd * 2 + (slot & 1)) * 128;
    const long m0  = (long)(slot >> 1) * 256;

    f32x4 acc[4][4] = {};

    const bf16_t* Ag[4];
    const bf16_t* Bg[2];
    #pragma unroll
    for (int i = 0; i < 4; ++i) {
        const int c   = i * 512 + tid;
        const int row = c >> 3;
        const int col = ((c & 7) ^ (row & 7)) * 8;
        Ag[i] = A + (m0 + row) * K + col;
    }
    #pragma unroll
    for (int i = 0; i < 2; ++i) {
        const int c   = i * 512 + tid;
        const int row = c >> 3;
        const int col = ((c & 7) ^ (row & 7)) * 8;
        Bg[i] = Bm + (n0 + row) * K + col;
    }

#define STAGE(t, bu) {                                                        \
    _Pragma("unroll") for (int i = 0; i < 4; ++i)                             \
        async_copy16(Ag[i] + (t) * 64, &As[bu][i * 4096 + w * 512]);          \
    _Pragma("unroll") for (int i = 0; i < 2; ++i)                             \
        async_copy16(Bg[i] + (t) * 64, &Bs[bu][i * 4096 + w * 512]); }

#define COMP(bu) {                                                            \
    _Pragma("unroll") for (int kc = 0; kc < 2; ++kc) {                        \
        bf16x8 af[4], bfr[4];                                                 \
        const int cs = ((kc * 4 + quad) ^ l7) * 8;                            \
        _Pragma("unroll") for (int t = 0; t < 4; ++t) {                       \
            af[t]  = *(const bf16x8*)&As[bu][(wm * 64 + t * 16 + l16) * 64 + cs]; \
            bfr[t] = *(const bf16x8*)&Bs[bu][(wn * 64 + t * 16 + l16) * 64 + cs]; \
        }                                                                     \
        _Pragma("unroll") for (int mt = 0; mt < 4; ++mt)                      \
            _Pragma("unroll") for (int nt = 0; nt < 4; ++nt)                  \
                acc[mt][nt] = __builtin_amdgcn_mfma_f32_16x16x32_bf16(        \
                    af[mt], bfr[nt], acc[mt][nt], 0, 0, 0); } }

    STAGE(0, 0); STAGE(1, 1);

    #pragma unroll 1
    for (int jb = 0; jb < 30; jb += 3) {
        VMC(6); BAR; STAGE(jb + 2, 2); COMP(0);
        VMC(6); BAR; STAGE(jb + 3, 0); COMP(1);
        VMC(6); BAR; STAGE(jb + 4, 1); COMP(2);
    }
    VMC(6); BAR; COMP(0);
    VMC(0); BAR; COMP(1);

#undef STAGE
#undef COMP

    #pragma unroll
    for (int mt = 0; mt < 4; ++mt)
        #pragma unroll
        for (int nt = 0; nt < 4; ++nt)
            #pragma unroll
            for (int r = 0; r < 4; ++r) {
                const long m = m0 + wm * 64 + mt * 16 + quad * 4 + r;
                const long n = n0 + wn * 64 + nt * 16 + l16;
                Cp[m * N + n] = acc[mt][nt][r];
            }
}

// ---------------------------------------------------------------------------
// Flash attention R17. Grid 512, 4 waves; 128-row Q tile. K and V^T both
// LDS double-buffered (R14 structure); last-iter refetch dropped.
// Ps swizzle FIXED: mask ((l16&3)<<2)^((l16&12)>>1) -- even (16B pairs
// preserved), 2-way-per-bank across l16 (free). LDS 80 KB -> 2 blocks/CU.
// ---------------------------------------------------------------------------
__global__ __launch_bounds__(256, 2)
void flash_attn(const bf16_t* __restrict__ Q, const bf16_t* __restrict__ Kg,
                const bf16_t* __restrict__ VT, bf16_t* __restrict__ O)
{
    constexpr int S = 2048, D = 2048;
    __shared__ bf16_t Kb[2][64 * 128];   // [k_row][d], chunk-swizzled
    __shared__ bf16_t Vb[2][128 * 64];   // [d][k_row], chunk-swizzled
    __shared__ bf16_t Ps[128 * 64];      // [q_row][k], XOR chunk-swizzled

    const int tid  = threadIdx.x;
    const int w    = tid >> 6, lane = tid & 63, l16 = lane & 15, quad = lane >> 4;
    const int l7   = l16 & 7;
    // Ps chunk swizzle (8B chunks): even mask, all row bits spread, 2-way max
    const int rsw  = ((l16 & 3) << 2) ^ ((l16 & 12) >> 1);

    const int id   = blockIdx.x;
    const int half = id >> 8;            // 0: qt 0..7, 1: qt 15..8
    const int rest = id & 255;
    const int xcd  = rest & 7;
    const int s    = rest >> 3;          // 0..31
    const int hh   = s & 3;
    const int qh   = s >> 2;             // 0..7
    const int qt   = half ? (15 - qh) : qh;
    const int bh   = xcd * 4 + hh;
    const int b    = bh >> 4, h = bh & 15;
    const int q0   = qt * 128;

    // Q fragments (B-operand): n = q (l16), k = d
    bf16x8 qf[2][4];
    {
        const bf16_t* qp = Q + (long)(b * S + q0 + w * 32 + l16) * D + h * 128 + quad * 8;
        #pragma unroll
        for (int qi = 0; qi < 2; ++qi)
            #pragma unroll
            for (int kk = 0; kk < 4; ++kk)
                qf[qi][kk] = *(const bf16x8*)(qp + qi * 16 * D + kk * 32);
    }

    // staging offsets (XOR chunk swizzle). K: 1024 chunks [64 rows][16 slots];
    // V^T: 1024 chunks [128 rows][8 slots].
    int koff[4], vof[4];
    #pragma unroll
    for (int i = 0; i < 4; ++i) {
        const int c  = i * 256 + tid;
        const int kr = c >> 4, cs = c & 15;
        const int cc = (cs & 8) | ((cs & 7) ^ (kr & 7));
        koff[i] = kr * D + cc * 8;
        const int d  = c >> 3, vs = c & 7;
        vof[i] = d * S + (vs ^ (d & 7)) * 8;
    }
    const bf16_t* Kst = Kg + (long)b * S * D + h * 128;
    const bf16_t* Vst = VT + (long)bh * 128 * S;

    f32x4 oacc[2][8] = {};
    float li[2] = { 0.f, 0.f };
    const float SC = 0.08838834764831845f * 1.44269504088896340f;

    const int nkt = 2 * qt + 2;

    // prologue: stage K[0], V[0] into buffer 0
    #pragma unroll
    for (int i = 0; i < 4; ++i) {
        async_copy16(Kst + koff[i], &Kb[0][i * 2048 + w * 512]);
        async_copy16(Vst + vof[i], &Vb[0][i * 2048 + w * 512]);
    }

    for (int kt = 0; kt < nkt; ++kt) {
        __syncthreads();   // drains prefetch issued 1 iter ago; guards bufs
        // ---- prefetch next tile (skipped on last iter) ----
        if (kt + 1 < nkt) {
            #pragma unroll
            for (int i = 0; i < 4; ++i) {
                async_copy16(Kst + (long)(kt + 1) * 64 * D + koff[i],
                             &Kb[(kt + 1) & 1][i * 2048 + w * 512]);
                async_copy16(Vst + (long)(kt + 1) * 64 + vof[i],
                             &Vb[(kt + 1) & 1][i * 2048 + w * 512]);
            }
        }

        const bool active = (kt * 64 <= q0 + w * 32 + 31);
        if (active) {
            // ---- S^T = K·Q^T ----
            f32x4 sc[4][2] = {};
            const bf16_t* Kcur = Kb[kt & 1];
            #pragma unroll
            for (int kk = 0; kk < 4; ++kk)
                #pragma unroll
                for (int mt = 0; mt < 4; ++mt) {
                    const int cc = kk * 4 + quad;
                    const bf16x8 kf = *(const bf16x8*)
                        &Kcur[(mt * 16 + l16) * 128 + ((cc & 8) | ((cc & 7) ^ l7)) * 8];
                    sc[mt][0] = __builtin_amdgcn_mfma_f32_16x16x32_bf16(
                        kf, qf[0][kk], sc[mt][0], 0, 0, 0);
                    sc[mt][1] = __builtin_amdgcn_mfma_f32_16x16x32_bf16(
                        kf, qf[1][kk], sc[mt][1], 0, 0, 0);
                }

            // ---- fixed-M softmax + packed P writes (swizzled chunks) ----
            #pragma unroll
            for (int qi = 0; qi < 2; ++qi) {
                const int qg = q0 + w * 32 + qi * 16 + l16;
                const int prow = w * 32 + qi * 16 + l16;
                float rs = 0.f;
                #pragma unroll
                for (int mt = 0; mt < 4; ++mt) {
                    bf16x4 pk;
                    #pragma unroll
                    for (int r = 0; r < 4; ++r) {
                        const int kg = kt * 64 + mt * 16 + quad * 4 + r;
                        const float p = (kg > qg) ? 0.f
                                      : exp2f(sc[mt][qi][r] * SC - 24.0f);
                        rs += p;
                        pk[r] = (bf16_t)p;
                    }
                    *(bf16x4*)&Ps[prow * 64 + ((mt * 4 + quad) ^ rsw) * 4] = pk;
                }
                li[qi] += rs;
            }

            // ---- O += P·V^T (V from LDS, same parity as K) ----
            const bf16_t* Vcur = Vb[kt & 1];
            #pragma unroll
            for (int ks = 0; ks < 2; ++ks) {
                const bf16x8 pf0 = *(const bf16x8*)
                    &Ps[(w * 32 + l16) * 64 + ((ks * 8 + quad * 2) ^ rsw) * 4];
                const bf16x8 pf1 = *(const bf16x8*)
                    &Ps[(w * 32 + 16 + l16) * 64 + ((ks * 8 + quad * 2) ^ rsw) * 4];
                #pragma unroll
                for (int nv = 0; nv < 8; ++nv) {
                    const bf16x8 vf = *(const bf16x8*)
                        &Vcur[(nv * 16 + l16) * 64 + ((ks * 4 + quad) ^ l7) * 8];
                    oacc[0][nv] = __builtin_amdgcn_mfma_f32_16x16x32_bf16(
                        pf0, vf, oacc[0][nv], 0, 0, 0);
                    oacc[1][nv] = __builtin_amdgcn_mfma_f32_16x16x32_bf16(
                        pf1, vf, oacc[1][nv], 0, 0, 0);
                }
            }
        }
    }

    // ---- epilogue: reduce li across quads, normalize, store ----
    #pragma unroll
    for (int qi = 0; qi < 2; ++qi) {
        li[qi] += __shfl_xor(li[qi], 16);
        li[qi] += __shfl_xor(li[qi], 32);
        const float inv = 1.0f / li[qi];
        #pragma unroll
        for (int r = 0; r < 4; ++r) {
            const float invr = __shfl(inv, quad * 4 + r);
            const long  row  = (long)(b * S + q0 + w * 32 + qi * 16 + quad * 4 + r);
            #pragma unroll
            for (int nv = 0; nv < 8; ++nv)
                O[row * D + h * 128 + nv * 16 + l16] = (bf16_t)(oacc[qi][nv][r] * invr);
        }
    }
}

// ---------------------------------------------------------------------------
extern "C" void kernel_launch(void* const* d_in, const int* in_sizes, int n_in,
                              void* d_out, int out_size, void* d_ws, size_t ws_size,
                              hipStream_t stream) {
    const float* x  = (const float*)d_in[0];
    const float* wq = (const float*)d_in[1];
    const float* wk = (const float*)d_in[2];
    const float* wv = (const float*)d_in[3];
    const float* wo = (const float*)d_in[4];
    const float* fc = (const float*)d_in[5];
    const float* fs = (const float*)d_in[6];

    char* ws = (char*)d_ws;
    bf16_t* xb  = (bf16_t*)(ws + 0);
    bf16_t* W3  = (bf16_t*)(ws + (16l << 20));
    bf16_t* wob = (bf16_t*)(ws + (40l << 20));
    bf16_t* Qb  = (bf16_t*)(ws + (48l << 20));
    bf16_t* Kb  = (bf16_t*)(ws + (64l << 20));
    bf16_t* VTb = (bf16_t*)(ws + (80l << 20));
    bf16_t* Ob  = xb;   // x dead after QKV projection

    cast_all<<<24576, 256, 0, stream>>>(x, wq, wk, wv, wo, xb, W3, wob);

    gemm_qkv<<<768, 512, 0, stream>>>(xb, W3, Qb, Kb, VTb, fc, fs);

    flash_attn<<<512, 256, 0, stream>>>(Qb, Kb, VTb, Ob);

    gemm_out<<<256, 512, 0, stream>>>(Ob, wob, (float*)d_out);
}